// Round 4
// baseline (197.006 us; speedup 1.0000x reference)
//
#include <hip/hip_runtime.h>

// Problem constants (from reference config)
#define FD 56          // depth samples: linspace(2, 58, 56)
#define FH 112         // 900 / 8
#define FW 200         // 1600 / 8
#define VD 16          // volume D
#define VH 200         // volume H
#define VW 200         // volume W
#define NC 32          // channels
#define NPIX (FH * FW)         // 22400 = 350 * 64 exactly
#define CSTRIDE (VD * VH * VW) // 640000 floats per channel

__global__ __launch_bounds__(256)
void VolumeTransform_3667902071054_kernel(const float* __restrict__ vol,
                                          const float* __restrict__ Km,
                                          const float* __restrict__ Tm,
                                          float* __restrict__ out) {
    // ---- compute fused projection matrix M = e2f @ T @ [[K^-1,0],[0,1]] ----
    __shared__ float sM[12];
    if (threadIdx.x == 0) {
        float a = Km[0], b = Km[1], c = Km[2];
        float d = Km[3], e = Km[4], f = Km[5];
        float g = Km[6], h = Km[7], i = Km[8];
        // adjugate / det -> K^-1
        float A00 = e * i - f * h, A01 = c * h - b * i, A02 = b * f - c * e;
        float A10 = f * g - d * i, A11 = a * i - c * g, A12 = c * d - a * f;
        float A20 = d * h - e * g, A21 = b * g - a * h, A22 = a * e - b * d;
        float det = a * A00 + b * A10 + c * A20;
        float r = 1.0f / det;
        float Ki[9] = {A00 * r, A01 * r, A02 * r,
                       A10 * r, A11 * r, A12 * r,
                       A20 * r, A21 * r, A22 * r};
        // R = T @ [[Ki,0],[0,1]]
        float R[4][4];
        for (int rr = 0; rr < 4; ++rr) {
            for (int cc = 0; cc < 3; ++cc)
                R[rr][cc] = Tm[rr * 4 + 0] * Ki[0 * 3 + cc]
                          + Tm[rr * 4 + 1] * Ki[1 * 3 + cc]
                          + Tm[rr * 4 + 2] * Ki[2 * 3 + cc];
            R[rr][3] = Tm[rr * 4 + 3];
        }
        // e2f: diag(2.5,2.5,2.5), trans (100,100,2.5)  [grid config, ratio=1]
        const float s[3] = {2.5f, 2.5f, 2.5f};
        const float t[3] = {100.0f, 100.0f, 2.5f};
        for (int rr = 0; rr < 3; ++rr)
            for (int cc = 0; cc < 4; ++cc)
                sM[rr * 4 + cc] = s[rr] * R[rr][cc] + t[rr] * R[3][cc];
    }
    __syncthreads();

    // 1D grid: 2800 blocks = 8 channel-groups (fast) x 350 pixel-groups
    const int cg  = blockIdx.x & 7;       // 0..7
    const int pg  = blockIdx.x >> 3;      // 0..349
    const int lane = threadIdx.x & 63;
    const int wv   = threadIdx.x >> 6;
    const int c    = cg * 4 + wv;         // 0..31
    const int p    = pg * 64 + lane;      // 0..22399
    const int py   = p / FW;
    const int px   = p - py * FW;

    const float gx = (float)px * (1599.0f / 199.0f); // linspace(0,1599,200)
    const float gy = (float)py * (899.0f / 111.0f);  // linspace(0,899,112)

    const float m00 = sM[0], m01 = sM[1], m02 = sM[2], m03 = sM[3];
    const float m10 = sM[4], m11 = sM[5], m12 = sM[6], m13 = sM[7];
    const float m20 = sM[8], m21 = sM[9], m22 = sM[10], m23 = sM[11];

    // feat(d) = gd * a + m[:,3]   (pts = [gx*gd, gy*gd, gd, 1])
    const float ax = m00 * gx + m01 * gy + m02;
    const float ay = m10 * gx + m11 * gy + m12;
    const float az = m20 * gx + m21 * gy + m22;

    const float* __restrict__ volc = vol + (size_t)c * CSTRIDE;
    float acc = 0.0f;

    for (int k = 0; k < FD; ++k) {
        const float gd = 2.0f + (float)k * (56.0f / 55.0f); // linspace(2,58,56)
        const float fx = ax * gd + m03; // W coordinate (normalization cancels)
        const float fy = ay * gd + m13; // H coordinate
        const float fz = az * gd + m23; // D coordinate

        // full-miss early out (boundary-exact: at fx==-1 or fx>=VW contribution is 0)
        if (!(fx > -1.0f && fx < (float)VW &&
              fy > -1.0f && fy < (float)VH &&
              fz > -1.0f && fz < (float)VD))
            continue;

        const float xf = floorf(fx), yf = floorf(fy), zf = floorf(fz);
        const float tx = fx - xf, ty = fy - yf, tz = fz - zf;
        const int ix = (int)xf, iy = (int)yf, iz = (int)zf; // each in [-1, dim-1]

        const float wx0 = (ix >= 0)      ? (1.0f - tx) : 0.0f;
        const float wx1 = (ix < VW - 1)  ? tx          : 0.0f;
        const float wy0 = (iy >= 0)      ? (1.0f - ty) : 0.0f;
        const float wy1 = (iy < VH - 1)  ? ty          : 0.0f;
        const float wz0 = (iz >= 0)      ? (1.0f - tz) : 0.0f;
        const float wz1 = (iz < VD - 1)  ? tz          : 0.0f;

        const int xi0 = max(ix, 0);
        const int xi1 = min(ix + 1, VW - 1);
        const int yo0 = max(iy, 0) * VW;
        const int yo1 = min(iy + 1, VH - 1) * VW;
        const int zo0 = max(iz, 0) * (VH * VW);
        const int zo1 = min(iz + 1, VD - 1) * (VH * VW);

        const float* b00 = volc + zo0 + yo0;
        const float* b01 = volc + zo0 + yo1;
        const float* b10 = volc + zo1 + yo0;
        const float* b11 = volc + zo1 + yo1;

        const float v000 = b00[xi0], v001 = b00[xi1];
        const float v010 = b01[xi0], v011 = b01[xi1];
        const float v100 = b10[xi0], v101 = b10[xi1];
        const float v110 = b11[xi0], v111 = b11[xi1];

        acc += wz0 * (wy0 * (wx0 * v000 + wx1 * v001) +
                      wy1 * (wx0 * v010 + wx1 * v011)) +
               wz1 * (wy0 * (wx0 * v100 + wx1 * v101) +
                      wy1 * (wx0 * v110 + wx1 * v111));
    }

    out[c * NPIX + p] = acc;
}

extern "C" void kernel_launch(void* const* d_in, const int* in_sizes, int n_in,
                              void* d_out, int out_size, void* d_ws, size_t ws_size,
                              hipStream_t stream) {
    (void)in_sizes; (void)n_in; (void)out_size; (void)d_ws; (void)ws_size;
    const float* vol = (const float*)d_in[0]; // (1,32,16,200,200) fp32
    const float* Km  = (const float*)d_in[1]; // (1,3,3) fp32
    const float* Tm  = (const float*)d_in[2]; // (1,4,4) fp32
    float* out = (float*)d_out;               // (1,32,112,200) fp32

    VolumeTransform_3667902071054_kernel<<<dim3(2800), dim3(256), 0, stream>>>(vol, Km, Tm, out);
}

// Round 5
// 165.638 us; speedup vs baseline: 1.1894x; 1.1894x over previous
//
#include <hip/hip_runtime.h>

// Problem constants (from reference config)
#define FD 56          // depth samples: linspace(2, 58, 56)
#define FH 112         // 900 / 8
#define FW 200         // 1600 / 8
#define VD 16          // volume D
#define VH 200         // volume H
#define VW 200         // volume W
#define NC 32          // channels
#define NPIX (FH * FW)         // 22400 = 350 * 64 exactly
#define CSTRIDE (VD * VH * VW) // 640000 floats per channel

typedef float f2v __attribute__((ext_vector_type(2)));
typedef f2v uf2v __attribute__((aligned(4)));   // 8B vector load, 4B-align safe

__global__ __launch_bounds__(256)
void VolumeTransform_3667902071054_kernel(const float* __restrict__ vol,
                                          const float* __restrict__ Km,
                                          const float* __restrict__ Tm,
                                          float* __restrict__ out) {
    // ---- fused projection matrix M = e2f @ T @ [[K^-1,0],[0,1]] ----
    __shared__ float sM[12];
    if (threadIdx.x == 0) {
        float a = Km[0], b = Km[1], c = Km[2];
        float d = Km[3], e = Km[4], f = Km[5];
        float g = Km[6], h = Km[7], i = Km[8];
        float A00 = e * i - f * h, A01 = c * h - b * i, A02 = b * f - c * e;
        float A10 = f * g - d * i, A11 = a * i - c * g, A12 = c * d - a * f;
        float A20 = d * h - e * g, A21 = b * g - a * h, A22 = a * e - b * d;
        float det = a * A00 + b * A10 + c * A20;
        float r = 1.0f / det;
        float Ki[9] = {A00 * r, A01 * r, A02 * r,
                       A10 * r, A11 * r, A12 * r,
                       A20 * r, A21 * r, A22 * r};
        float R[4][4];
        for (int rr = 0; rr < 4; ++rr) {
            for (int cc = 0; cc < 3; ++cc)
                R[rr][cc] = Tm[rr * 4 + 0] * Ki[0 * 3 + cc]
                          + Tm[rr * 4 + 1] * Ki[1 * 3 + cc]
                          + Tm[rr * 4 + 2] * Ki[2 * 3 + cc];
            R[rr][3] = Tm[rr * 4 + 3];
        }
        const float s[3] = {2.5f, 2.5f, 2.5f};
        const float t[3] = {100.0f, 100.0f, 2.5f};
        for (int rr = 0; rr < 3; ++rr)
            for (int cc = 0; cc < 4; ++cc)
                sM[rr * 4 + cc] = s[rr] * R[rr][cc] + t[rr] * R[3][cc];
    }
    __syncthreads();

    // 1400 blocks = 4 channel-pair-groups (fast) x 350 pixel-groups.
    // Each thread: 1 pixel x 2 consecutive channels (weights computed once).
    const int cg   = blockIdx.x & 3;      // 0..3
    const int pg   = blockIdx.x >> 2;     // 0..349
    const int lane = threadIdx.x & 63;
    const int wv   = threadIdx.x >> 6;
    const int c0   = (cg * 4 + wv) * 2;   // 0,2,..,30
    const int p    = pg * 64 + lane;      // 0..22399
    const int py   = p / FW;
    const int px   = p - py * FW;

    const float gx = (float)px * (1599.0f / 199.0f);
    const float gy = (float)py * (899.0f / 111.0f);

    const float m03 = sM[3], m13 = sM[7], m23 = sM[11];
    const float ax = sM[0] * gx + sM[1] * gy + sM[2];
    const float ay = sM[4] * gx + sM[5] * gy + sM[6];
    const float az = sM[8] * gx + sM[9] * gy + sM[10];

    const float* __restrict__ volc0 = vol + (size_t)c0 * CSTRIDE;
    const float* __restrict__ volc1 = volc0 + CSTRIDE;
    float acc0 = 0.0f, acc1 = 0.0f;

    for (int k = 0; k < FD; ++k) {
        const float gd = 2.0f + (float)k * (56.0f / 55.0f);
        const float fx = ax * gd + m03;
        const float fy = ay * gd + m13;
        const float fz = az * gd + m23;

        if (!(fx > -1.0f && fx < (float)VW &&
              fy > -1.0f && fy < (float)VH &&
              fz > -1.0f && fz < (float)VD))
            continue;

        const float xf = floorf(fx), yf = floorf(fy), zf = floorf(fz);
        const float tx = fx - xf, ty = fy - yf, tz = fz - zf;
        const int ix = (int)xf, iy = (int)yf, iz = (int)zf;

        const float wy0 = (iy >= 0)     ? (1.0f - ty) : 0.0f;
        const float wy1 = (iy < VH - 1) ? ty          : 0.0f;
        const float wz0 = (iz >= 0)     ? (1.0f - tz) : 0.0f;
        const float wz1 = (iz < VD - 1) ? tz          : 0.0f;

        // combined (z,y) corner weights
        const float w00 = wz0 * wy0, w01 = wz0 * wy1;
        const float w10 = wz1 * wy0, w11 = wz1 * wy1;

        const int yo0 = max(iy, 0) * VW;
        const int yo1 = min(iy + 1, VH - 1) * VW;
        const int zo0 = max(iz, 0) * (VH * VW);
        const int zo1 = min(iz + 1, VD - 1) * (VH * VW);

        float h00a, h01a, h10a, h11a;   // x-lerped values, channel c0
        float h00b, h01b, h10b, h11b;   // channel c0+1

        if (ix >= 0 && ix < VW - 1) {
            // interior in x: one 8B load per (z,y) corner per channel
            const int o00 = zo0 + yo0 + ix, o01 = zo0 + yo1 + ix;
            const int o10 = zo1 + yo0 + ix, o11 = zo1 + yo1 + ix;
            const float wx0 = 1.0f - tx, wx1 = tx;
            f2v a00 = *(const uf2v*)(volc0 + o00);
            f2v a01 = *(const uf2v*)(volc0 + o01);
            f2v a10 = *(const uf2v*)(volc0 + o10);
            f2v a11 = *(const uf2v*)(volc0 + o11);
            f2v b00 = *(const uf2v*)(volc1 + o00);
            f2v b01 = *(const uf2v*)(volc1 + o01);
            f2v b10 = *(const uf2v*)(volc1 + o10);
            f2v b11 = *(const uf2v*)(volc1 + o11);
            h00a = wx0 * a00.x + wx1 * a00.y;  h01a = wx0 * a01.x + wx1 * a01.y;
            h10a = wx0 * a10.x + wx1 * a10.y;  h11a = wx0 * a11.x + wx1 * a11.y;
            h00b = wx0 * b00.x + wx1 * b00.y;  h01b = wx0 * b01.x + wx1 * b01.y;
            h10b = wx0 * b10.x + wx1 * b10.y;  h11b = wx0 * b11.x + wx1 * b11.y;
        } else {
            // x border: clamped scalar loads with masked weights
            const float wx0 = (ix >= 0)     ? (1.0f - tx) : 0.0f;
            const float wx1 = (ix < VW - 1) ? tx          : 0.0f;
            const int xi0 = max(ix, 0);
            const int xi1 = min(ix + 1, VW - 1);
            h00a = wx0 * volc0[zo0 + yo0 + xi0] + wx1 * volc0[zo0 + yo0 + xi1];
            h01a = wx0 * volc0[zo0 + yo1 + xi0] + wx1 * volc0[zo0 + yo1 + xi1];
            h10a = wx0 * volc0[zo1 + yo0 + xi0] + wx1 * volc0[zo1 + yo0 + xi1];
            h11a = wx0 * volc0[zo1 + yo1 + xi0] + wx1 * volc0[zo1 + yo1 + xi1];
            h00b = wx0 * volc1[zo0 + yo0 + xi0] + wx1 * volc1[zo0 + yo0 + xi1];
            h01b = wx0 * volc1[zo0 + yo1 + xi0] + wx1 * volc1[zo0 + yo1 + xi1];
            h10b = wx0 * volc1[zo1 + yo0 + xi0] + wx1 * volc1[zo1 + yo0 + xi1];
            h11b = wx0 * volc1[zo1 + yo1 + xi0] + wx1 * volc1[zo1 + yo1 + xi1];
        }

        acc0 += w00 * h00a + w01 * h01a + w10 * h10a + w11 * h11a;
        acc1 += w00 * h00b + w01 * h01b + w10 * h10b + w11 * h11b;
    }

    out[c0 * NPIX + p]       = acc0;
    out[(c0 + 1) * NPIX + p] = acc1;
}

extern "C" void kernel_launch(void* const* d_in, const int* in_sizes, int n_in,
                              void* d_out, int out_size, void* d_ws, size_t ws_size,
                              hipStream_t stream) {
    (void)in_sizes; (void)n_in; (void)out_size; (void)d_ws; (void)ws_size;
    const float* vol = (const float*)d_in[0]; // (1,32,16,200,200) fp32
    const float* Km  = (const float*)d_in[1]; // (1,3,3) fp32
    const float* Tm  = (const float*)d_in[2]; // (1,4,4) fp32
    float* out = (float*)d_out;               // (1,32,112,200) fp32

    VolumeTransform_3667902071054_kernel<<<dim3(1400), dim3(256), 0, stream>>>(vol, Km, Tm, out);
}